// Round 4
// baseline (94.043 us; speedup 1.0000x reference)
//
#include <hip/hip_runtime.h>
#include <cstdint>
#include <cstddef>

typedef _Float16 f16;
typedef f16 f16x8 __attribute__((ext_vector_type(8)));
typedef f16 f16x4 __attribute__((ext_vector_type(4)));
typedef float floatx4 __attribute__((ext_vector_type(4)));

#define GAS __attribute__((address_space(1)))
#define LAS __attribute__((address_space(3)))

static constexpr int LSEQ = 2048;
static constexpr int NH   = 8;
static constexpr int DH   = 64;
static constexpr int DM   = 512;
static constexpr int WIN  = 64;
static constexpr int MR   = 4 * LSEQ;  // 8192 rows (B*L)

// ---------------------------------------------------------------- cast x -> f16
__global__ __launch_bounds__(256) void cast_x_kernel(const float* __restrict__ x,
                                                     f16* __restrict__ xb) {
    int i = blockIdx.x * 256 + threadIdx.x;      // each thread: 4 elements
    float4 v = ((const float4*)x)[i];
    f16x4 o = { (f16)v.x, (f16)v.y, (f16)v.z, (f16)v.w };
    ((f16x4*)xb)[i] = o;
}

// ------------------------------------------------- transpose W (512x512) -> Wt f16
__global__ void wt_kernel(const float* __restrict__ Wq, const float* __restrict__ Wk,
                          const float* __restrict__ Wv, const float* __restrict__ Wo,
                          f16* __restrict__ wt) {
    __shared__ float tile[32][33];
    int z = blockIdx.z;
    const float* W = z == 0 ? Wq : z == 1 ? Wk : z == 2 ? Wv : Wo;
    f16* out = wt + (size_t)z * DM * DM;
    int c0 = blockIdx.x * 32, r0 = blockIdx.y * 32;
    int tx = threadIdx.x, ty = threadIdx.y;   // block (32, 8)
    #pragma unroll
    for (int i = 0; i < 32; i += 8)
        tile[ty + i][tx] = W[(size_t)(r0 + ty + i) * DM + c0 + tx];
    __syncthreads();
    #pragma unroll
    for (int i = 0; i < 32; i += 8)
        out[(size_t)(c0 + ty + i) * DM + r0 + tx] = (f16)tile[tx][ty + i];
}

// ---------------------------------------------------------------- GEMM 128x128, BK=256
// Fat-K, few-event structure: K=512 in 2 iterations of BK=256, each split into two
// 128-wide k-halves. Single 128KB LDS buffer [khalf][128row][128k]; 4 half-stages
// total, counted vmcnt(16) so each drain is covered by the previous half's MFMA.
// LDS layout: As[half*16384 + row*128 + k]; staging chunk q=i*256+tid -> row=q>>4,
// ci=q&15, XOR-swizzled source col (ci^(row&7)), lane-linear LDS dest (rule #21).
template <bool QKV>
__global__ __launch_bounds__(256, 1) void gemm_kernel(
    const f16* __restrict__ A, const f16* __restrict__ Bt_base,
    const float* __restrict__ b0, const float* __restrict__ b1,
    const float* __restrict__ b2,
    f16* __restrict__ out_q, f16* __restrict__ out_k, f16* __restrict__ out_vt,
    float* __restrict__ out_f) {
    const int z = QKV ? blockIdx.z : 0;
    const f16* __restrict__ Bt = Bt_base + (size_t)z * (DM * DM);
    const float* __restrict__ bias = QKV ? (z == 0 ? b0 : z == 1 ? b1 : b2) : b0;

    __shared__ f16 As[2 * 128 * 128];   // 64 KB  [khalf][row][k-in-half]
    __shared__ f16 Bs[2 * 128 * 128];   // 64 KB

    const int tid  = threadIdx.x;
    const int wid  = tid >> 6;
    const int lane = tid & 63;
    const int l15  = lane & 15;
    const int l4   = lane >> 4;
    const int m0   = blockIdx.y * 128;
    const int n0   = blockIdx.x * 128;
    const int wr   = wid >> 1, wc = wid & 1;

    floatx4 acc[4][4] = {};

    // stage one 128x128 half-tile of one matrix: 8 global_load_lds per thread
    auto stage = [&](const f16* __restrict__ src, f16* lds, int r0, int k0, int half) {
        #pragma unroll
        for (int i = 0; i < 8; ++i) {
            int q   = i * 256 + tid;          // 0..2047
            int row = q >> 4, ci = q & 15;
            int cis = ci ^ (row & 7);
            const f16* g = src + (size_t)(r0 + row) * DM + k0 + half * 128 + cis * 8;
            f16* l = lds + half * 16384 + (i * 256 + wid * 64) * 8;  // +lane*16B by HW
            __builtin_amdgcn_global_load_lds((const GAS void*)g, (LAS void*)l, 16, 0, 0);
        }
    };
    // consume one k-half: 4 ks-steps x 16 MFMA
    auto compute_half = [&](int half) {
        #pragma unroll
        for (int ks = 0; ks < 4; ++ks) {
            f16x8 af[4], bfr[4];
            #pragma unroll
            for (int m = 0; m < 4; ++m) {
                int row = wr * 64 + m * 16 + l15;
                int cis = (ks * 4 + l4) ^ (row & 7);
                af[m] = *(const f16x8*)(&As[half * 16384 + row * 128 + cis * 8]);
            }
            #pragma unroll
            for (int n = 0; n < 4; ++n) {
                int row = wc * 64 + n * 16 + l15;
                int cis = (ks * 4 + l4) ^ (row & 7);
                bfr[n] = *(const f16x8*)(&Bs[half * 16384 + row * 128 + cis * 8]);
            }
            #pragma unroll
            for (int m = 0; m < 4; ++m)
                #pragma unroll
                for (int n = 0; n < 4; ++n)
                    acc[m][n] = __builtin_amdgcn_mfma_f32_16x16x32_f16(af[m], bfr[n], acc[m][n], 0, 0, 0);
        }
    };
    auto wait_bar = [&](int n) {
        if (n == 16) asm volatile("s_waitcnt vmcnt(16)" ::: "memory");
        else         asm volatile("s_waitcnt vmcnt(0)" ::: "memory");
        __builtin_amdgcn_sched_barrier(0);
        __builtin_amdgcn_s_barrier();
        __builtin_amdgcn_sched_barrier(0);
    };

    // S0,S1 (iter0 h0,h1) -> compute h0 | S2 (iter1 h0) -> compute h1 | S3 -> ...
    stage(A, As, m0, 0, 0);  stage(Bt, Bs, n0, 0, 0);     // S0: 16/thread
    stage(A, As, m0, 0, 1);  stage(Bt, Bs, n0, 0, 1);     // S1: 32 outstanding
    wait_bar(16);                                          // S0 landed (all waves)
    compute_half(0);
    __builtin_amdgcn_s_barrier();                          // h0 free for overwrite
    __builtin_amdgcn_sched_barrier(0);
    stage(A, As, m0, 256, 0); stage(Bt, Bs, n0, 256, 0);   // S2 into h0
    wait_bar(16);                                          // S1 landed
    compute_half(1);
    __builtin_amdgcn_s_barrier();                          // h1 free
    __builtin_amdgcn_sched_barrier(0);
    stage(A, As, m0, 256, 1); stage(Bt, Bs, n0, 256, 1);   // S3 into h1
    wait_bar(16);                                          // S2 landed
    compute_half(0);
    wait_bar(0);                                           // S3 landed
    compute_half(1);

    // epilogue; D layout: col = lane&15, row = (lane>>4)*4 + r  (m89-verified)
    #pragma unroll
    for (int n = 0; n < 4; ++n) {
        int gcol = n0 + wc * 64 + n * 16 + l15;
        float bias_v = bias[gcol];
        #pragma unroll
        for (int m = 0; m < 4; ++m) {
            int grow0 = m0 + wr * 64 + m * 16 + l4 * 4;
            #pragma unroll
            for (int r = 0; r < 4; ++r) {
                int grow = grow0 + r;
                float v = acc[m][n][r] + bias_v;
                if constexpr (QKV) {
                    int b = grow >> 11, lp = grow & (LSEQ - 1);
                    int h = gcol >> 6,  d  = gcol & (DH - 1);
                    int bh = b * NH + h;
                    if (z == 0)       // Q, pre-scaled by 1/sqrt(Dh) (exact pow2)
                        out_q[((size_t)bh * LSEQ + lp) * DH + d] = (f16)(v * 0.125f);
                    else if (z == 1)  // K: [bh][l][d]
                        out_k[((size_t)bh * LSEQ + lp) * DH + d] = (f16)v;
                    else              // V transposed: [bh][d][l]
                        out_vt[((size_t)bh * DH + d) * LSEQ + lp] = (f16)v;
                } else {
                    out_f[(size_t)grow * DM + gcol] = v;
                }
            }
        }
    }
}

// ---------------------------------------------------------------- windowed attention
// block: (64 queries of one bh), 4 waves x 16 queries; key window = 192 wide
__global__ __launch_bounds__(256) void attn_kernel(const f16* __restrict__ Qb,
                                                   const f16* __restrict__ Kb,
                                                   const f16* __restrict__ Vt,
                                                   f16* __restrict__ Ob) {
    const int bh     = blockIdx.y;
    const int q0blk  = blockIdx.x * 64;
    const int wid    = threadIdx.x >> 6;
    const int lane   = threadIdx.x & 63;
    const int l15    = lane & 15, l4 = lane >> 4;
    const int qbase  = q0blk + wid * 16;
    const int kstart = q0blk - WIN;

    const f16* __restrict__ Q = Qb + (size_t)bh * LSEQ * DH;
    const f16* __restrict__ K = Kb + (size_t)bh * LSEQ * DH;
    const f16* __restrict__ V = Vt + (size_t)bh * DH * LSEQ;

    __shared__ f16 Pl[4][16][232];   // 232*2B = 464B row stride: 16B-aligned, bank-spread

    // Q fragments (A operand): row = l15, k = ks*32 + l4*8 + i
    f16x8 qf[2];
    #pragma unroll
    for (int ks = 0; ks < 2; ++ks)
        qf[ks] = *(const f16x8*)(Q + (size_t)(qbase + l15) * DH + ks * 32 + l4 * 8);

    // S = Q K^T : 12 n-tiles of 16 keys
    floatx4 sc[12] = {};
    #pragma unroll
    for (int nt = 0; nt < 12; ++nt) {
        int key = kstart + nt * 16 + l15;
        int kcl = key < 0 ? 0 : (key > LSEQ - 1 ? LSEQ - 1 : key);
        #pragma unroll
        for (int ks = 0; ks < 2; ++ks) {
            f16x8 kf = *(const f16x8*)(K + (size_t)kcl * DH + ks * 32 + l4 * 8);
            sc[nt] = __builtin_amdgcn_mfma_f32_16x16x32_f16(qf[ks], kf, sc[nt], 0, 0, 0);
        }
    }

    // mask + softmax. Row q = qbase + l4*4 + r lives in the 16 lanes sharing l4.
    float mx[4] = {-1e30f, -1e30f, -1e30f, -1e30f};
    #pragma unroll
    for (int nt = 0; nt < 12; ++nt) {
        int key = kstart + nt * 16 + l15;
        #pragma unroll
        for (int r = 0; r < 4; ++r) {
            int q = qbase + l4 * 4 + r;
            int dist = key - q; dist = dist < 0 ? -dist : dist;
            bool valid = (key >= 0) && (key < LSEQ) && (dist <= WIN);
            float s = valid ? sc[nt][r] : -1e30f;
            sc[nt][r] = s;
            mx[r] = fmaxf(mx[r], s);
        }
    }
    #pragma unroll
    for (int r = 0; r < 4; ++r)
        #pragma unroll
        for (int m = 1; m < 16; m <<= 1)
            mx[r] = fmaxf(mx[r], __shfl_xor(mx[r], m, 64));
    float sm[4] = {0.f, 0.f, 0.f, 0.f};
    #pragma unroll
    for (int nt = 0; nt < 12; ++nt)
        #pragma unroll
        for (int r = 0; r < 4; ++r) {
            float p = __expf(sc[nt][r] - mx[r]);
            sc[nt][r] = p;
            sm[r] += p;
        }
    #pragma unroll
    for (int r = 0; r < 4; ++r) {
        #pragma unroll
        for (int m = 1; m < 16; m <<= 1)
            sm[r] += __shfl_xor(sm[r], m, 64);
        sm[r] = 1.f / sm[r];
    }

    // P -> LDS in A-fragment-friendly layout
    #pragma unroll
    for (int nt = 0; nt < 12; ++nt)
        #pragma unroll
        for (int r = 0; r < 4; ++r)
            Pl[wid][l4 * 4 + r][nt * 16 + l15] = (f16)(sc[nt][r] * sm[r]);
    __syncthreads();

    // O = P V : A-frag from LDS (contiguous), B-frag from Vt (contiguous keys)
    floatx4 oc[4] = {};
    #pragma unroll
    for (int ks = 0; ks < 6; ++ks) {
        f16x8 pf = *(const f16x8*)(&Pl[wid][l15][ks * 32 + l4 * 8]);
        int kb0 = kstart + ks * 32 + l4 * 8;
        int kbc = (kb0 < 0 || kb0 > LSEQ - 8) ? 0 : kb0;  // whole chunk valid or P==0
        #pragma unroll
        for (int dt = 0; dt < 4; ++dt) {
            f16x8 vf = *(const f16x8*)(V + (size_t)(dt * 16 + l15) * LSEQ + kbc);
            oc[dt] = __builtin_amdgcn_mfma_f32_16x16x32_f16(pf, vf, oc[dt], 0, 0, 0);
        }
    }

    // write O in [B][L][H*64] f16 (A operand of final GEMM)
    int b = bh >> 3, h = bh & 7;
    #pragma unroll
    for (int dt = 0; dt < 4; ++dt) {
        int d = dt * 16 + l15;
        #pragma unroll
        for (int r = 0; r < 4; ++r) {
            int q = qbase + l4 * 4 + r;
            Ob[((size_t)b * LSEQ + q) * DM + h * DH + d] = (f16)oc[dt][r];
        }
    }
}

// ---------------------------------------------------------------- launch
extern "C" void kernel_launch(void* const* d_in, const int* in_sizes, int n_in,
                              void* d_out, int out_size, void* d_ws, size_t ws_size,
                              hipStream_t stream) {
    const float* x  = (const float*)d_in[0];
    const float* Wq = (const float*)d_in[1];
    const float* bq = (const float*)d_in[2];
    const float* Wk = (const float*)d_in[3];
    const float* bk = (const float*)d_in[4];
    const float* Wv = (const float*)d_in[5];
    const float* bv = (const float*)d_in[6];
    const float* Wo = (const float*)d_in[7];
    const float* bo = (const float*)d_in[8];
    float* out = (float*)d_out;

    char* ws = (char*)d_ws;
    f16* xb = (f16*)(ws);                       // 8 MB  [8192][512]
    f16* wt = (f16*)(ws + (8ull << 20));        // 2 MB  WqT,WkT,WvT,WoT
    f16* qb = (f16*)(ws + (10ull << 20));       // 8 MB  [32][2048][64], pre-scaled
    f16* kb = (f16*)(ws + (18ull << 20));       // 8 MB  [32][2048][64]
    f16* vt = (f16*)(ws + (26ull << 20));       // 8 MB  [32][64][2048]
    f16* ob = (f16*)(ws + (34ull << 20));       // 8 MB  [8192][512]

    cast_x_kernel<<<dim3(MR * DM / 4 / 256), 256, 0, stream>>>(x, xb);
    wt_kernel<<<dim3(16, 16, 4), dim3(32, 8), 0, stream>>>(Wq, Wk, Wv, Wo, wt);
    gemm_kernel<true><<<dim3(4, 64, 3), 256, 0, stream>>>(
        xb, wt, bq, bk, bv, qb, kb, vt, nullptr);
    attn_kernel<<<dim3(LSEQ / 64, 32), 256, 0, stream>>>(qb, kb, vt, ob);
    gemm_kernel<false><<<dim3(4, 64, 1), 256, 0, stream>>>(
        ob, wt + 3ull * DM * DM, bo, bo, bo, nullptr, nullptr, nullptr, out);
}

// Round 5
// 86.623 us; speedup vs baseline: 1.0857x; 1.0857x over previous
//
#include <hip/hip_runtime.h>
#include <cstdint>
#include <cstddef>

typedef _Float16 f16;
typedef f16 f16x8 __attribute__((ext_vector_type(8)));
typedef f16 f16x4 __attribute__((ext_vector_type(4)));
typedef float floatx4 __attribute__((ext_vector_type(4)));

#define GAS __attribute__((address_space(1)))
#define LAS __attribute__((address_space(3)))

static constexpr int LSEQ = 2048;
static constexpr int NH   = 8;
static constexpr int DH   = 64;
static constexpr int DM   = 512;
static constexpr int WIN  = 64;
static constexpr int MR   = 4 * LSEQ;  // 8192 rows (B*L)

// ------------------------------------------- prep: cast x->f16  +  transpose W->f16
// blocks 0..4095: cast 1024 floats each.  blocks 4096..5119: one 32x32 W tile each.
__global__ __launch_bounds__(256) void prep_kernel(
    const float* __restrict__ x, f16* __restrict__ xb,
    const float* __restrict__ Wq, const float* __restrict__ Wk,
    const float* __restrict__ Wv, const float* __restrict__ Wo,
    f16* __restrict__ wt) {
    __shared__ float tile[32][33];
    int bid = blockIdx.x;
    if (bid < 4096) {
        int i = bid * 256 + threadIdx.x;      // 4 elements/thread
        float4 v = ((const float4*)x)[i];
        f16x4 o = { (f16)v.x, (f16)v.y, (f16)v.z, (f16)v.w };
        ((f16x4*)xb)[i] = o;
    } else {
        int id = bid - 4096;
        int z  = id >> 8, t = id & 255;
        const float* W = z == 0 ? Wq : z == 1 ? Wk : z == 2 ? Wv : Wo;
        f16* out = wt + (size_t)z * DM * DM;
        int c0 = (t & 15) * 32, r0 = (t >> 4) * 32;
        int tx = threadIdx.x & 31, ty = threadIdx.x >> 5;
        #pragma unroll
        for (int i = 0; i < 32; i += 8)
            tile[ty + i][tx] = W[(size_t)(r0 + ty + i) * DM + c0 + tx];
        __syncthreads();
        #pragma unroll
        for (int i = 0; i < 32; i += 8)
            out[(size_t)(c0 + ty + i) * DM + r0 + tx] = (f16)tile[tx][ty + i];
    }
}

// ---------------------------------------------------------------- GEMM 128x128, BK=64
// R3 counted-vmcnt double-buffered loop + T1 chunked-XCD swizzle: 1-D grid,
// lin = (hw&7)*(nwg/8) + hw/8 gives each XCD a CONTIGUOUS run of logical tiles,
// so the 4 n-tiles sharing an A-panel hit the same XCD's L2 (staging-BW fix).
// Logical decode: n = lin&3, m = (lin>>2)&63, z = lin>>8.
template <bool QKV>
__global__ __launch_bounds__(256, 2) void gemm_kernel(
    const f16* __restrict__ A, const f16* __restrict__ Bt_base,
    const float* __restrict__ b0, const float* __restrict__ b1,
    const float* __restrict__ b2,
    f16* __restrict__ out_q, f16* __restrict__ out_k, f16* __restrict__ out_vt,
    float* __restrict__ out_f) {
    const int chunk = gridDim.x >> 3;
    const int hw  = blockIdx.x;
    const int lin = (hw & 7) * chunk + (hw >> 3);
    const int n0  = (lin & 3) * 128;
    const int m0  = ((lin >> 2) & 63) * 128;
    const int z   = QKV ? (lin >> 8) : 0;

    const f16* __restrict__ Bt = Bt_base + (size_t)z * (DM * DM);
    const float* __restrict__ bias = QKV ? (z == 0 ? b0 : z == 1 ? b1 : b2) : b0;

    __shared__ f16 As[2][128 * 64];
    __shared__ f16 Bs[2][128 * 64];

    const int tid  = threadIdx.x;
    const int wid  = tid >> 6;
    const int lane = tid & 63;
    const int l15  = lane & 15;
    const int l4   = lane >> 4;
    const int wr   = wid >> 1, wc = wid & 1;

    floatx4 acc[4][4] = {};

    const int c_ = wid * 64 + lane;   // base chunk id (0..255)

    // XOR-swizzled SOURCE + linear LDS dest (rule #21)
    auto stage = [&](int buf, int k0) {
        #pragma unroll
        for (int i = 0; i < 4; ++i) {
            int c   = i * 256 + c_;
            int row = c >> 3, cw = c & 7;
            int cs  = cw ^ (row & 7);
            const f16* ga = A  + (size_t)(m0 + row) * DM + k0 + cs * 8;
            const f16* gb = Bt + (size_t)(n0 + row) * DM + k0 + cs * 8;
            f16* la = &As[buf][(i * 256 + wid * 64) * 8];
            f16* lb = &Bs[buf][(i * 256 + wid * 64) * 8];
            __builtin_amdgcn_global_load_lds((const GAS void*)ga, (LAS void*)la, 16, 0, 0);
            __builtin_amdgcn_global_load_lds((const GAS void*)gb, (LAS void*)lb, 16, 0, 0);
        }
    };
    auto compute = [&](int buf) {
        #pragma unroll
        for (int ks = 0; ks < 2; ++ks) {
            f16x8 af[4], bfr[4];
            #pragma unroll
            for (int m = 0; m < 4; ++m) {
                int row = wr * 64 + m * 16 + l15;
                int kc  = (ks * 4 + l4) ^ (row & 7);
                af[m] = *(const f16x8*)(&As[buf][row * 64 + kc * 8]);
            }
            #pragma unroll
            for (int n = 0; n < 4; ++n) {
                int row = wc * 64 + n * 16 + l15;
                int kc  = (ks * 4 + l4) ^ (row & 7);
                bfr[n] = *(const f16x8*)(&Bs[buf][row * 64 + kc * 8]);
            }
            #pragma unroll
            for (int m = 0; m < 4; ++m)
                #pragma unroll
                for (int n = 0; n < 4; ++n)
                    acc[m][n] = __builtin_amdgcn_mfma_f32_16x16x32_f16(af[m], bfr[n], acc[m][n], 0, 0, 0);
        }
    };

    stage(0, 0);
    stage(1, 64);
    #pragma unroll
    for (int t = 0; t < 8; ++t) {
        if (t < 7) asm volatile("s_waitcnt vmcnt(8)" ::: "memory");
        else       asm volatile("s_waitcnt vmcnt(0)" ::: "memory");
        __builtin_amdgcn_sched_barrier(0);
        __builtin_amdgcn_s_barrier();      // all waves' buffer-t loads landed
        __builtin_amdgcn_sched_barrier(0);
        compute(t & 1);
        if (t < 6) {
            __builtin_amdgcn_s_barrier();  // everyone done reading buf t&1
            __builtin_amdgcn_sched_barrier(0);
            stage(t & 1, (t + 2) * 64);    // overwrite it with tile t+2
        }
    }

    // epilogue; D layout: col = lane&15, row = (lane>>4)*4 + r  (m89-verified)
    #pragma unroll
    for (int n = 0; n < 4; ++n) {
        int gcol = n0 + wc * 64 + n * 16 + l15;
        float bias_v = bias[gcol];
        #pragma unroll
        for (int m = 0; m < 4; ++m) {
            int grow0 = m0 + wr * 64 + m * 16 + l4 * 4;
            #pragma unroll
            for (int r = 0; r < 4; ++r) {
                int grow = grow0 + r;
                float v = acc[m][n][r] + bias_v;
                if constexpr (QKV) {
                    int b = grow >> 11, lp = grow & (LSEQ - 1);
                    int h = gcol >> 6,  d  = gcol & (DH - 1);
                    int bh = b * NH + h;
                    if (z == 0)       // Q, pre-scaled by 1/sqrt(Dh) (exact pow2)
                        out_q[((size_t)bh * LSEQ + lp) * DH + d] = (f16)(v * 0.125f);
                    else if (z == 1)  // K: [bh][l][d]
                        out_k[((size_t)bh * LSEQ + lp) * DH + d] = (f16)v;
                    else              // V transposed: [bh][d][l]
                        out_vt[((size_t)bh * DH + d) * LSEQ + lp] = (f16)v;
                } else {
                    out_f[(size_t)grow * DM + gcol] = v;
                }
            }
        }
    }
}

// ---------------------------------------------------------------- windowed attention
// 1-D grid 1024 + chunked-XCD swizzle (4 heads' K/V per XCD -> L2-resident).
// block: (64 queries of one bh), 4 waves x 16 queries; key window = 192 wide
__global__ __launch_bounds__(256) void attn_kernel(const f16* __restrict__ Qb,
                                                   const f16* __restrict__ Kb,
                                                   const f16* __restrict__ Vt,
                                                   f16* __restrict__ Ob) {
    const int hw  = blockIdx.x;
    const int lin = (hw & 7) * 128 + (hw >> 3);
    const int bh    = lin >> 5;
    const int q0blk = (lin & 31) * 64;
    const int wid    = threadIdx.x >> 6;
    const int lane   = threadIdx.x & 63;
    const int l15    = lane & 15, l4 = lane >> 4;
    const int qbase  = q0blk + wid * 16;
    const int kstart = q0blk - WIN;

    const f16* __restrict__ Q = Qb + (size_t)bh * LSEQ * DH;
    const f16* __restrict__ K = Kb + (size_t)bh * LSEQ * DH;
    const f16* __restrict__ V = Vt + (size_t)bh * DH * LSEQ;

    __shared__ f16 Pl[4][16][232];   // 464B row stride: 16B-aligned, bank-spread

    // Q fragments (A operand): row = l15, k = ks*32 + l4*8 + i
    f16x8 qf[2];
    #pragma unroll
    for (int ks = 0; ks < 2; ++ks)
        qf[ks] = *(const f16x8*)(Q + (size_t)(qbase + l15) * DH + ks * 32 + l4 * 8);

    // S = Q K^T : 12 n-tiles of 16 keys
    floatx4 sc[12] = {};
    #pragma unroll
    for (int nt = 0; nt < 12; ++nt) {
        int key = kstart + nt * 16 + l15;
        int kcl = key < 0 ? 0 : (key > LSEQ - 1 ? LSEQ - 1 : key);
        #pragma unroll
        for (int ks = 0; ks < 2; ++ks) {
            f16x8 kf = *(const f16x8*)(K + (size_t)kcl * DH + ks * 32 + l4 * 8);
            sc[nt] = __builtin_amdgcn_mfma_f32_16x16x32_f16(qf[ks], kf, sc[nt], 0, 0, 0);
        }
    }

    // mask + softmax. Row q = qbase + l4*4 + r lives in the 16 lanes sharing l4.
    float mx[4] = {-1e30f, -1e30f, -1e30f, -1e30f};
    #pragma unroll
    for (int nt = 0; nt < 12; ++nt) {
        int key = kstart + nt * 16 + l15;
        #pragma unroll
        for (int r = 0; r < 4; ++r) {
            int q = qbase + l4 * 4 + r;
            int dist = key - q; dist = dist < 0 ? -dist : dist;
            bool valid = (key >= 0) && (key < LSEQ) && (dist <= WIN);
            float s = valid ? sc[nt][r] : -1e30f;
            sc[nt][r] = s;
            mx[r] = fmaxf(mx[r], s);
        }
    }
    #pragma unroll
    for (int r = 0; r < 4; ++r)
        #pragma unroll
        for (int m = 1; m < 16; m <<= 1)
            mx[r] = fmaxf(mx[r], __shfl_xor(mx[r], m, 64));
    float sm[4] = {0.f, 0.f, 0.f, 0.f};
    #pragma unroll
    for (int nt = 0; nt < 12; ++nt)
        #pragma unroll
        for (int r = 0; r < 4; ++r) {
            float p = __expf(sc[nt][r] - mx[r]);
            sc[nt][r] = p;
            sm[r] += p;
        }
    #pragma unroll
    for (int r = 0; r < 4; ++r) {
        #pragma unroll
        for (int m = 1; m < 16; m <<= 1)
            sm[r] += __shfl_xor(sm[r], m, 64);
        sm[r] = 1.f / sm[r];
    }

    // P -> LDS in A-fragment-friendly layout
    #pragma unroll
    for (int nt = 0; nt < 12; ++nt)
        #pragma unroll
        for (int r = 0; r < 4; ++r)
            Pl[wid][l4 * 4 + r][nt * 16 + l15] = (f16)(sc[nt][r] * sm[r]);
    __syncthreads();

    // O = P V : A-frag from LDS (contiguous), B-frag from Vt (contiguous keys)
    floatx4 oc[4] = {};
    #pragma unroll
    for (int ks = 0; ks < 6; ++ks) {
        f16x8 pf = *(const f16x8*)(&Pl[wid][l15][ks * 32 + l4 * 8]);
        int kb0 = kstart + ks * 32 + l4 * 8;
        int kbc = (kb0 < 0 || kb0 > LSEQ - 8) ? 0 : kb0;  // whole chunk valid or P==0
        #pragma unroll
        for (int dt = 0; dt < 4; ++dt) {
            f16x8 vf = *(const f16x8*)(V + (size_t)(dt * 16 + l15) * LSEQ + kbc);
            oc[dt] = __builtin_amdgcn_mfma_f32_16x16x32_f16(pf, vf, oc[dt], 0, 0, 0);
        }
    }

    // write O in [B][L][H*64] f16 (A operand of final GEMM)
    int b = bh >> 3, h = bh & 7;
    #pragma unroll
    for (int dt = 0; dt < 4; ++dt) {
        int d = dt * 16 + l15;
        #pragma unroll
        for (int r = 0; r < 4; ++r) {
            int q = qbase + l4 * 4 + r;
            Ob[((size_t)b * LSEQ + q) * DM + h * DH + d] = (f16)oc[dt][r];
        }
    }
}

// ---------------------------------------------------------------- launch
extern "C" void kernel_launch(void* const* d_in, const int* in_sizes, int n_in,
                              void* d_out, int out_size, void* d_ws, size_t ws_size,
                              hipStream_t stream) {
    const float* x  = (const float*)d_in[0];
    const float* Wq = (const float*)d_in[1];
    const float* bq = (const float*)d_in[2];
    const float* Wk = (const float*)d_in[3];
    const float* bk = (const float*)d_in[4];
    const float* Wv = (const float*)d_in[5];
    const float* bv = (const float*)d_in[6];
    const float* Wo = (const float*)d_in[7];
    const float* bo = (const float*)d_in[8];
    float* out = (float*)d_out;

    char* ws = (char*)d_ws;
    f16* xb = (f16*)(ws);                       // 8 MB  [8192][512]
    f16* wt = (f16*)(ws + (8ull << 20));        // 2 MB  WqT,WkT,WvT,WoT
    f16* qb = (f16*)(ws + (10ull << 20));       // 8 MB  [32][2048][64], pre-scaled
    f16* kb = (f16*)(ws + (18ull << 20));       // 8 MB  [32][2048][64]
    f16* vt = (f16*)(ws + (26ull << 20));       // 8 MB  [32][64][2048]
    f16* ob = (f16*)(ws + (34ull << 20));       // 8 MB  [8192][512]

    prep_kernel<<<dim3(5120), 256, 0, stream>>>(x, xb, Wq, Wk, Wv, Wo, wt);
    gemm_kernel<true><<<dim3(768), 256, 0, stream>>>(
        xb, wt, bq, bk, bv, qb, kb, vt, nullptr);
    attn_kernel<<<dim3(1024), 256, 0, stream>>>(qb, kb, vt, ob);
    gemm_kernel<false><<<dim3(256), 256, 0, stream>>>(
        ob, wt + 3ull * DM * DM, bo, bo, bo, nullptr, nullptr, nullptr, out);
}